// Round 1
// baseline (274.390 us; speedup 1.0000x reference)
//
#include <hip/hip_runtime.h>
#include <hip/hip_bf16.h>

#define NN 16384
#define DD 64
#define TILES 256   // NN / 64

constexpr float F_EPS_PD   = 1e-6f;
constexpr float F_EPS_NORM = 1e-6f;

using bf16x8 = __attribute__((ext_vector_type(8))) short;
using f32x4  = __attribute__((ext_vector_type(4))) float;

__device__ __forceinline__ float wave_sum_f(float v) {
    #pragma unroll
    for (int o = 32; o >= 1; o >>= 1) v += __shfl_xor(v, o);
    return v;
}

// ---------------------------------------------------------------------------
// Kernel 1: per-row normalize; emit bf16 copy and combined u/vc terms.
//   u[i]  = sq_i + 2*eps*s_i
//   vc[j] = sq_j - 2*eps*s_j + D*eps*eps
// so d2(i,j) = u[i] + vc[j] - 2*gram(i,j)
// ---------------------------------------------------------------------------
__global__ __launch_bounds__(256) void norm_kernel(
    const float* __restrict__ emb, float* __restrict__ u,
    float* __restrict__ vc, __hip_bfloat16* __restrict__ ebf) {
    int row  = blockIdx.x * 4 + (threadIdx.x >> 6);
    int lane = threadIdx.x & 63;
    float x  = emb[(size_t)row * DD + lane];
    float n2 = wave_sum_f(x * x);
    float m  = fmaxf(sqrtf(n2), F_EPS_NORM);
    float e  = x / m;
    float sq = wave_sum_f(e * e);
    float s  = wave_sum_f(e);
    ebf[(size_t)row * DD + lane] = __float2bfloat16(e);
    if (lane == 0) {
        u[row]  = sq + 2.0f * F_EPS_PD * s;
        vc[row] = sq - 2.0f * F_EPS_PD * s + (float)DD * F_EPS_PD * F_EPS_PD;
    }
}

// ---------------------------------------------------------------------------
// Kernel 2: exact fp32 positive-pair loss. One wave per row i.
// ---------------------------------------------------------------------------
__global__ __launch_bounds__(256) void pos_kernel(
    const float* __restrict__ emb, const int* __restrict__ pos_idx,
    const float* __restrict__ u, const float* __restrict__ vc,
    float* __restrict__ posP) {
    int i    = blockIdx.x * 4 + (threadIdx.x >> 6);
    int lane = threadIdx.x & 63;
    int j    = pos_idx[i];
    float xi = emb[(size_t)i * DD + lane];
    float xj = emb[(size_t)j * DD + lane];
    float n2i = wave_sum_f(xi * xi);
    float n2j = wave_sum_f(xj * xj);
    float dot = wave_sum_f(xi * xj);
    if (lane == 0) {
        float mi = fmaxf(sqrtf(n2i), F_EPS_NORM);
        float mj = fmaxf(sqrtf(n2j), F_EPS_NORM);
        float g  = dot / (mi * mj);
        float d2 = u[i] + vc[j] - 2.0f * g;
        posP[i]  = fmaxf(d2, 0.0f);
    }
}

// ---------------------------------------------------------------------------
// Kernel 3: pairwise tiles. Block = 64x64 tile (4 waves, each a 16x64 strip).
// Upper-triangle tile-pairs only; off-diagonal weighted x2 (gram symmetric;
// the antisymmetric 2*eps*(s_i-s_j) term's effect on hinge^2 is ~1e-3 total,
// vs ~655 numerator error budget).
// ---------------------------------------------------------------------------
__global__ __launch_bounds__(256) void pair_kernel(
    const short* __restrict__ ebf, const float* __restrict__ u,
    const float* __restrict__ vc, const int* __restrict__ lab,
    float* __restrict__ negP, unsigned int* __restrict__ cntP) {
    int ti = blockIdx.x, tj = blockIdx.y;
    int blin = tj * TILES + ti;
    if (tj < ti) {                    // inactive half: still write partials
        if (threadIdx.x == 0) { negP[blin] = 0.0f; cntP[blin] = 0u; }
        return;
    }
    int w    = threadIdx.x >> 6;
    int lane = threadIdx.x & 63;
    int lrow = lane & 15, lkh = lane >> 4;
    int bi = ti * 64 + w * 16;
    int bj = tj * 64;

    // A fragment: rows of the i-block (lane&15), contiguous K-chunk.
    const short* arow = ebf + (size_t)(bi + lrow) * DD + lkh * 8;
    bf16x8 a0 = *(const bf16x8*)(arow);
    bf16x8 a1 = *(const bf16x8*)(arow + 32);

    f32x4 acc[4];
    #pragma unroll
    for (int t = 0; t < 4; ++t) {
        const short* brow = ebf + (size_t)(bj + t * 16 + lrow) * DD + lkh * 8;
        bf16x8 b0 = *(const bf16x8*)(brow);
        bf16x8 b1 = *(const bf16x8*)(brow + 32);
        f32x4 c = {0.f, 0.f, 0.f, 0.f};
        c = __builtin_amdgcn_mfma_f32_16x16x32_bf16(a0, b0, c, 0, 0, 0);
        c = __builtin_amdgcn_mfma_f32_16x16x32_bf16(a1, b1, c, 0, 0, 0);
        acc[t] = c;
    }

    // Epilogue. C/D layout: col = lane&15, row = (lane>>4)*4 + reg  [m89].
    float uu[4]; int li[4];
    #pragma unroll
    for (int r = 0; r < 4; ++r) {
        int i = bi + lkh * 4 + r;
        uu[r] = u[i]; li[r] = lab[i];
    }
    float hacc = 0.0f; unsigned int cnt = 0;
    #pragma unroll
    for (int t = 0; t < 4; ++t) {
        int j = bj + t * 16 + lrow;
        float vj = vc[j]; int lj = lab[j];
        #pragma unroll
        for (int r = 0; r < 4; ++r) {
            float d2  = fmaf(-2.0f, acc[t][r], uu[r] + vj);
            bool neg  = (li[r] != lj);
            cnt += neg ? 1u : 0u;
            if (__ballot(d2 < 1.0f)) {          // rare path (~0.2% of groups)
                float dist = sqrtf(fmaxf(d2, 1e-12f));
                float h    = fmaxf(1.0f - dist, 0.0f);
                hacc = neg ? fmaf(h, h, hacc) : hacc;
            }
        }
    }
    hacc = wave_sum_f(hacc);
    #pragma unroll
    for (int o = 32; o >= 1; o >>= 1) cnt += __shfl_xor(cnt, o);

    __shared__ float sneg[4];
    __shared__ unsigned int scnt[4];
    if (lane == 0) { sneg[w] = hacc; scnt[w] = cnt; }
    __syncthreads();
    if (threadIdx.x == 0) {
        float tn = sneg[0] + sneg[1] + sneg[2] + sneg[3];
        unsigned int tc = scnt[0] + scnt[1] + scnt[2] + scnt[3];
        float wgt = (ti == tj) ? 1.0f : 2.0f;
        negP[blin] = tn * wgt;
        cntP[blin] = (ti == tj) ? tc : tc * 2u;
    }
}

// ---------------------------------------------------------------------------
// Kernel 4: final single-block reduction -> scalar loss.
// ---------------------------------------------------------------------------
__global__ __launch_bounds__(256) void reduce_kernel(
    const float* __restrict__ posP, const float* __restrict__ negP,
    const unsigned int* __restrict__ cntP, float* __restrict__ out) {
    int t = threadIdx.x;
    float ps = 0.f, ns = 0.f;
    unsigned int cs = 0;
    for (int i = t; i < NN; i += 256) ps += posP[i];
    for (int i = t; i < TILES * TILES; i += 256) { ns += negP[i]; cs += cntP[i]; }
    ps = wave_sum_f(ps);
    ns = wave_sum_f(ns);
    #pragma unroll
    for (int o = 32; o >= 1; o >>= 1) cs += __shfl_xor(cs, o);

    __shared__ float sp[4], sn[4];
    __shared__ unsigned int sc[4];
    int w = t >> 6, lane = t & 63;
    if (lane == 0) { sp[w] = ps; sn[w] = ns; sc[w] = cs; }
    __syncthreads();
    if (t == 0) {
        float pos = sp[0] + sp[1] + sp[2] + sp[3];
        float neg = sn[0] + sn[1] + sn[2] + sn[3];
        unsigned long long cnt = (unsigned long long)sc[0] + sc[1] + sc[2] + sc[3];
        float ncomp = (float)((unsigned long long)NN + cnt);
        out[0] = (pos + neg) / ncomp;
    }
}

// ---------------------------------------------------------------------------
// ws layout (bytes):
//   u    @ 0        : 16384*4  = 65536
//   vc   @ 65536    : 65536
//   ebf  @ 131072   : 16384*64*2 = 2097152
//   posP @ 2228224  : 65536
//   negP @ 2293760  : 262144
//   cntP @ 2555904  : 262144
//   total 2818048 bytes (~2.7 MB)
// ---------------------------------------------------------------------------
extern "C" void kernel_launch(void* const* d_in, const int* in_sizes, int n_in,
                              void* d_out, int out_size, void* d_ws, size_t ws_size,
                              hipStream_t stream) {
    const float* emb = (const float*)d_in[0];
    const int* lab   = (const int*)d_in[1];
    const int* pidx  = (const int*)d_in[2];
    float* out = (float*)d_out;
    char* ws = (char*)d_ws;
    float*          u    = (float*)(ws);
    float*          vc   = (float*)(ws + 65536);
    __hip_bfloat16* ebf  = (__hip_bfloat16*)(ws + 131072);
    float*          posP = (float*)(ws + 2228224);
    float*          negP = (float*)(ws + 2293760);
    unsigned int*   cntP = (unsigned int*)(ws + 2555904);

    norm_kernel<<<NN / 4, 256, 0, stream>>>(emb, u, vc, ebf);
    pos_kernel<<<NN / 4, 256, 0, stream>>>(emb, pidx, u, vc, posP);
    pair_kernel<<<dim3(TILES, TILES), 256, 0, stream>>>(
        (const short*)ebf, u, vc, lab, negP, cntP);
    reduce_kernel<<<1, 256, 0, stream>>>(posP, negP, cntP, out);
}

// Round 2
// 103.218 us; speedup vs baseline: 2.6583x; 2.6583x over previous
//
#include <hip/hip_runtime.h>
#include <hip/hip_bf16.h>

#define NN 16384
#define DD 64
#define TT 128                 // 128-row tiles: NN/128
#define NTRI ((TT*(TT+1))/2)   // 8256 triangular tile-pairs
#define NBLK 1024              // persistent blocks (all resident)
#define NPOSB (NN/4)           // norm blocks (4 rows each)

constexpr float F_EPS_PD   = 1e-6f;
constexpr float F_EPS_NORM = 1e-6f;

using bf16x8 = __attribute__((ext_vector_type(8))) short;
using f32x4  = __attribute__((ext_vector_type(4))) float;

__device__ __forceinline__ float wave_sum_f(float v) {
    #pragma unroll
    for (int o = 32; o >= 1; o >>= 1) v += __shfl_xor(v, o);
    return v;
}

__device__ __forceinline__ int tri_off(int t) { return t * TT - (t * (t - 1)) / 2; }

// ---------------------------------------------------------------------------
// Kernel 1: per-row normalize + bf16 copy + u/vc terms + exact fp32 pos loss.
//   u[i]  = sq_i + 2*eps*s_i
//   vc[j] = sq_j - 2*eps*s_j + D*eps*eps      (d2 = u_i + vc_j - 2*gram)
// pos pair (i, pidx[i]) computed from raw emb (no cross-row dependency).
// ---------------------------------------------------------------------------
__global__ __launch_bounds__(256) void norm_kernel(
    const float* __restrict__ emb, const int* __restrict__ pidx,
    float* __restrict__ u, float* __restrict__ vc,
    __hip_bfloat16* __restrict__ ebf, float* __restrict__ posP) {
    int w    = threadIdx.x >> 6;
    int row  = blockIdx.x * 4 + w;
    int lane = threadIdx.x & 63;
    int j    = pidx[row];
    float x  = emb[(size_t)row * DD + lane];
    float xj = emb[(size_t)j   * DD + lane];

    float n2  = wave_sum_f(x * x);
    float sx  = wave_sum_f(x);
    float n2j = wave_sum_f(xj * xj);
    float sxj = wave_sum_f(xj);
    float dot = wave_sum_f(x * xj);

    float m  = fmaxf(sqrtf(n2),  F_EPS_NORM);
    float mj = fmaxf(sqrtf(n2j), F_EPS_NORM);
    ebf[(size_t)row * DD + lane] = __float2bfloat16(x / m);

    __shared__ float spos[4];
    if (lane == 0) {
        float sq  = n2 / (m * m);
        float sqj = n2j / (mj * mj);
        float s   = sx / m;
        float sj  = sxj / mj;
        float g   = dot / (m * mj);
        u[row]  = sq + 2.0f * F_EPS_PD * s;
        vc[row] = sq - 2.0f * F_EPS_PD * s + (float)DD * F_EPS_PD * F_EPS_PD;
        float d2p = sq + sqj - 2.0f * g + 2.0f * F_EPS_PD * (s - sj)
                  + (float)DD * F_EPS_PD * F_EPS_PD;
        spos[w] = fmaxf(d2p, 0.0f);
    }
    __syncthreads();
    if (threadIdx.x == 0)
        posP[blockIdx.x] = spos[0] + spos[1] + spos[2] + spos[3];
}

// ---------------------------------------------------------------------------
// Kernel 2: persistent pairwise blocks. Each block grid-strides the 8256
// triangular 128x128 tile-pairs; wave w covers rows [w*32, w*32+32) as two
// 16-row strips (A-frags reused across the 8 column sub-tiles). Hinge/count
// accumulate in registers across ALL pairs; one reduce+write per block.
// Off-diagonal tiles weighted x2 (gram symmetric; the antisymmetric
// 2*eps*(s_i-s_j) term's effect on hinge^2 is ~0.1 total vs ~655 budget).
// ---------------------------------------------------------------------------
__global__ __launch_bounds__(256) void pair_kernel(
    const short* __restrict__ ebf, const float* __restrict__ u,
    const float* __restrict__ vc, const int* __restrict__ lab,
    float* __restrict__ negP, unsigned int* __restrict__ cntP) {
    int w    = threadIdx.x >> 6;
    int lane = threadIdx.x & 63;
    int lrow = lane & 15, lkh = lane >> 4;

    float hacc = 0.0f;
    unsigned int cnt = 0;

    for (int k = blockIdx.x; k < NTRI; k += NBLK) {
        // decode triangular index -> (ti, tj)
        int ti = (int)(128.5f - sqrtf(128.5f * 128.5f - 2.0f * (float)k));
        ti = ti < 0 ? 0 : (ti > TT - 1 ? TT - 1 : ti);
        while (tri_off(ti) > k) --ti;
        while (ti < TT - 1 && tri_off(ti + 1) <= k) ++ti;
        int tj = ti + (k - tri_off(ti));

        int bi = ti * 128 + w * 32;
        int bj = tj * 128;

        const short* ab = ebf + (size_t)(bi + lrow) * DD + lkh * 8;
        bf16x8 a00 = *(const bf16x8*)(ab);
        bf16x8 a01 = *(const bf16x8*)(ab + 32);
        bf16x8 a10 = *(const bf16x8*)(ab + 16 * DD);
        bf16x8 a11 = *(const bf16x8*)(ab + 16 * DD + 32);

        float uu0[4], uu1[4]; int li0[4], li1[4];
        #pragma unroll
        for (int r = 0; r < 4; ++r) {
            int i0 = bi + lkh * 4 + r;
            uu0[r] = u[i0];      li0[r] = lab[i0];
            uu1[r] = u[i0 + 16]; li1[r] = lab[i0 + 16];
        }

        const short* bb = ebf + (size_t)(bj + lrow) * DD + lkh * 8;
        float hp = 0.0f; unsigned int cp = 0;

        #pragma unroll
        for (int t = 0; t < 8; ++t) {
            bf16x8 b0 = *(const bf16x8*)(bb + t * 16 * DD);
            bf16x8 b1 = *(const bf16x8*)(bb + t * 16 * DD + 32);
            f32x4 c0 = {0.f, 0.f, 0.f, 0.f};
            c0 = __builtin_amdgcn_mfma_f32_16x16x32_bf16(a00, b0, c0, 0, 0, 0);
            c0 = __builtin_amdgcn_mfma_f32_16x16x32_bf16(a01, b1, c0, 0, 0, 0);
            f32x4 c1 = {0.f, 0.f, 0.f, 0.f};
            c1 = __builtin_amdgcn_mfma_f32_16x16x32_bf16(a10, b0, c1, 0, 0, 0);
            c1 = __builtin_amdgcn_mfma_f32_16x16x32_bf16(a11, b1, c1, 0, 0, 0);

            int j = bj + t * 16 + lrow;
            float vj = vc[j]; int lj = lab[j];
            #pragma unroll
            for (int r = 0; r < 4; ++r) {
                float d2a = fmaf(-2.0f, c0[r], uu0[r] + vj);
                float d2b = fmaf(-2.0f, c1[r], uu1[r] + vj);
                bool nga = (li0[r] != lj);
                bool ngb = (li1[r] != lj);
                cp += (nga ? 1u : 0u) + (ngb ? 1u : 0u);
                if (__ballot(d2a < 1.0f || d2b < 1.0f)) {   // rare (~0.2%)
                    float da = sqrtf(fmaxf(d2a, 1e-12f));
                    float ha = fmaxf(1.0f - da, 0.0f);
                    hp = nga ? fmaf(ha, ha, hp) : hp;
                    float db = sqrtf(fmaxf(d2b, 1e-12f));
                    float hb = fmaxf(1.0f - db, 0.0f);
                    hp = ngb ? fmaf(hb, hb, hp) : hp;
                }
            }
        }
        if (ti == tj) { hacc += hp;               cnt += cp;      }
        else          { hacc = fmaf(2.f, hp, hacc); cnt += cp * 2u; }
    }

    hacc = wave_sum_f(hacc);
    #pragma unroll
    for (int o = 32; o >= 1; o >>= 1) cnt += __shfl_xor(cnt, o);

    __shared__ float sneg[4];
    __shared__ unsigned int scnt[4];
    if (lane == 0) { sneg[w] = hacc; scnt[w] = cnt; }
    __syncthreads();
    if (threadIdx.x == 0) {
        negP[blockIdx.x] = sneg[0] + sneg[1] + sneg[2] + sneg[3];
        cntP[blockIdx.x] = scnt[0] + scnt[1] + scnt[2] + scnt[3];
    }
}

// ---------------------------------------------------------------------------
// Kernel 3: final reduction (posP: 4096, negP/cntP: 1024) -> scalar loss.
// ---------------------------------------------------------------------------
__global__ __launch_bounds__(256) void reduce_kernel(
    const float* __restrict__ posP, const float* __restrict__ negP,
    const unsigned int* __restrict__ cntP, float* __restrict__ out) {
    int t = threadIdx.x;
    float ps = 0.f, ns = 0.f;
    unsigned long long cs = 0;
    for (int i = t; i < NPOSB; i += 256) ps += posP[i];
    for (int i = t; i < NBLK; i += 256) { ns += negP[i]; cs += cntP[i]; }
    ps = wave_sum_f(ps);
    ns = wave_sum_f(ns);
    #pragma unroll
    for (int o = 32; o >= 1; o >>= 1) cs += __shfl_xor(cs, o);

    __shared__ float sp[4], sn[4];
    __shared__ unsigned long long sc[4];
    int w = t >> 6, lane = t & 63;
    if (lane == 0) { sp[w] = ps; sn[w] = ns; sc[w] = cs; }
    __syncthreads();
    if (t == 0) {
        float pos = sp[0] + sp[1] + sp[2] + sp[3];
        float neg = sn[0] + sn[1] + sn[2] + sn[3];
        unsigned long long cnt = sc[0] + sc[1] + sc[2] + sc[3];
        float ncomp = (float)((unsigned long long)NN + cnt);
        out[0] = (pos + neg) / ncomp;
    }
}

// ---------------------------------------------------------------------------
// ws layout (bytes):
//   u    @ 0        : 65536
//   vc   @ 65536    : 65536
//   ebf  @ 131072   : 2097152
//   posP @ 2228224  : 16384   (NPOSB=4096 floats)
//   negP @ 2244608  : 4096    (NBLK floats)
//   cntP @ 2248704  : 4096
//   total ~2.25 MB
// ---------------------------------------------------------------------------
extern "C" void kernel_launch(void* const* d_in, const int* in_sizes, int n_in,
                              void* d_out, int out_size, void* d_ws, size_t ws_size,
                              hipStream_t stream) {
    const float* emb = (const float*)d_in[0];
    const int* lab   = (const int*)d_in[1];
    const int* pidx  = (const int*)d_in[2];
    float* out = (float*)d_out;
    char* ws = (char*)d_ws;
    float*          u    = (float*)(ws);
    float*          vc   = (float*)(ws + 65536);
    __hip_bfloat16* ebf  = (__hip_bfloat16*)(ws + 131072);
    float*          posP = (float*)(ws + 2228224);
    float*          negP = (float*)(ws + 2244608);
    unsigned int*   cntP = (unsigned int*)(ws + 2248704);

    norm_kernel<<<NPOSB, 256, 0, stream>>>(emb, pidx, u, vc, ebf, posP);
    pair_kernel<<<NBLK, 256, 0, stream>>>((const short*)ebf, u, vc, lab, negP, cntP);
    reduce_kernel<<<1, 256, 0, stream>>>(posP, negP, cntP, out);
}